// Round 7
// baseline (371.556 us; speedup 1.0000x reference)
//
#include <hip/hip_runtime.h>
#include <math.h>

typedef __attribute__((ext_vector_type(8))) short short8;
typedef __attribute__((ext_vector_type(4))) float f32x4;
typedef __attribute__((ext_vector_type(2))) unsigned int u32x2;
typedef __attribute__((ext_vector_type(4))) unsigned int u32x4;

#define E_NUM 16
constexpr int CAPS[E_NUM] = {1024,512,1024,256,1024,512,128,1024,512,1024,256,512,1024,128,64,512};
constexpr int OFFS[E_NUM] = {0,1024,1536,2560,2816,3840,4352,4480,5504,6016,7040,7296,7808,8832,8960,9024};
constexpr int cdiv_(int a, int b){ return (a + b - 1) / b; }
constexpr int ilog2_(int v){ int l = 0; while ((1 << l) < v) ++l; return l; }

__device__ __forceinline__ unsigned int cvt_pk_bf16(float a, float b){
  unsigned int r;
  asm("v_cvt_pk_bf16_f32 %0, %1, %2" : "=v"(r) : "v"(a), "v"(b));
  return r;
}

typedef __attribute__((address_space(1))) const unsigned char gas_u8;
typedef __attribute__((address_space(3))) unsigned char las_u8;
__device__ __forceinline__ void gl_lds16(const void* g, void* l){
  __builtin_amdgcn_global_load_lds((gas_u8*)g, (las_u8*)l, 16, 0, 0);
}

// x fp32 -> bf16 (RNE), 8 elems/thread, grid-stride
__global__ __launch_bounds__(256) void cvt_bf16_kernel(const float* __restrict__ x,
                                                       unsigned short* __restrict__ xb, int n8)
{
  int i = blockIdx.x * blockDim.x + threadIdx.x;
  const int stride = gridDim.x * blockDim.x;
  for (; i < n8; i += stride) {
    f32x4 a = *reinterpret_cast<const f32x4*>(x + (size_t)i * 8);
    f32x4 b = *reinterpret_cast<const f32x4*>(x + (size_t)i * 8 + 4);
    u32x2 lo, hi;
    lo[0] = cvt_pk_bf16(a[0], a[1]); lo[1] = cvt_pk_bf16(a[2], a[3]);
    hi[0] = cvt_pk_bf16(b[0], b[1]); hi[1] = cvt_pk_bf16(b[2], b[3]);
    *reinterpret_cast<u32x2*>(xb + (size_t)i * 8)     = lo;
    *reinterpret_cast<u32x2*>(xb + (size_t)i * 8 + 4) = hi;
  }
}

// C = A @ W^T per expert.  A: [tokens][KDIM] bf16 via global_load_lds (or fp32
// reg-staged fallback).  W: [E][NDIM][KDIM] fp32 staged RAW via global_load_lds
// (16 KB fp32 tile), converted to bf16 in-register after the fragment read.
// Out: bf16 h with GELU, or fp32 + bias (KS>1: split-K, unsafeAtomicAdd, bias/KS).
// Swizzles (16B-block XOR, applied by pre-swizzled gl_lds SOURCE + swizzled read):
//   A rows 64B  (4 blocks):  phys = blk ^ (row&3)
//   B rows 128B (8 blocks):  phys = blk ^ (row&7)
// Both put every wave64 b128 read/write at the 8-requests-per-4-bank floor.
template<bool A_GLDS, bool GELU_OUT, int TM, int NDIM, int KDIM, int LOG_GN, int NWG, int KS>
__global__ __launch_bounds__(256, 3)
void expert_gemm(const void* __restrict__ Av, const float* __restrict__ W,
                 const float* __restrict__ bias, void* __restrict__ Outv)
{
  constexpr int A_BYTES = TM * 64;     // bf16 tile: TM x 32 x 2B
  constexpr int B_BYTES = 128 * 128;   // fp32 tile: 128 x 32 x 4B
  constexpr int GN   = 1 << LOG_GN;
  constexpr int MFR  = TM / 32;
  constexpr int NT   = KDIM / (KS * 32);
  constexpr int NWG1 = NWG / KS;
  static_assert(NWG % 8 == 0, "grid must be divisible by 8 for XCD swizzle");
  static_assert(!GELU_OUT || (2 * A_BYTES + 2 * B_BYTES) >= 128 * 128 * 2, "GELU needs 32KB");
  static_assert(!GELU_OUT || KS == 1, "GELU path is KS=1 only");

  __shared__ __align__(16) char smem[2 * A_BYTES + 2 * B_BYTES];   // 48 KB @ TM=128

  const int tid  = threadIdx.x;
  const int braw = blockIdx.x;
  const int t = (braw & 7) * (NWG / 8) + (braw >> 3);   // bijective XCD swizzle

  const int kc    = t / NWG1;
  const int tt    = t % NWG1;
  const int kbase = kc * (KDIM / KS);

  // ---- locate (expert, m0, n0): m-fastest within groups of GN n-panels ----
  int m0 = 0, n0 = 0, Me = 0, tok0 = 0;
  size_t wbase = 0, bbase = 0;
  {
    int acc0 = 0;
    #pragma unroll
    for (int i = 0; i < E_NUM; ++i) {
      const int mt  = cdiv_(CAPS[i], TM);
      const int lmt = ilog2_(mt);
      const int nb  = mt * (NDIM / 128);
      if (tt >= acc0 && tt < acc0 + nb) {
        const int loc = tt - acc0;
        const int g   = loc >> (lmt + LOG_GN);
        const int rem = loc & ((mt << LOG_GN) - 1);
        m0   = (rem >> LOG_GN) * TM;
        n0   = ((g << LOG_GN) | (rem & (GN - 1))) * 128;
        Me   = CAPS[i];
        tok0 = OFFS[i];
        wbase = (size_t)i * NDIM * KDIM;
        bbase = (size_t)i * NDIM;
      }
      acc0 += nb;
    }
  }
  const float* Wb = W + wbase;

  const int lane = tid & 63;
  const int wv   = tid >> 6;

  const unsigned short* Ah = (const unsigned short*)Av;
  const float*          Af = (const float*)Av;

  // --- B: raw fp32 global -> LDS via gl_lds (pre-swizzled source) ---
  auto stageB = [&](int buf, int kt) {
    const float* Bg = Wb + (size_t)n0 * KDIM + kbase + kt * 32;
    char* dst0 = smem + 2 * A_BYTES + buf * B_BYTES;
    #pragma unroll
    for (int j = 0; j < 4; ++j) {
      const int rbase = wv * 32 + j * 8;           // 8 rows of 128B per inst
      const int r     = rbase + (lane >> 3);
      const int lblk  = (lane & 7) ^ (r & 7);      // involution
      gl_lds16((const void*)(Bg + (size_t)r * KDIM + lblk * 4), (void*)(dst0 + rbase * 128));
    }
  };

  // --- A: bf16 global -> LDS via gl_lds (pre-swizzled source) ---
  auto stageA = [&](int buf, int kt) {
    const unsigned short* Ag = Ah + (size_t)(tok0 + m0) * KDIM + kbase + kt * 32;
    char* dst0 = smem + buf * A_BYTES;
    #pragma unroll
    for (int j = 0; j < TM / 64; ++j) {
      const int rbase = wv * (TM / 4) + j * 16;    // 16 rows of 64B per inst
      const int r     = rbase + (lane >> 2);
      const int lblk  = (lane & 3) ^ (r & 3);
      gl_lds16((const void*)(Ag + (size_t)r * KDIM + lblk * 8), (void*)(dst0 + rbase * 64));
    }
  };

  // --- fallback A: fp32 reg-staged + cvt + swizzled ds_write ---
  const int sr = tid >> 3;
  const int sc = (tid & 7) * 8;                    // byte col in 64B row
  f32x4 ra[MFR];
  auto loadA_reg = [&](int kt) {
    const int k0 = kbase + kt * 32;
    #pragma unroll
    for (int i = 0; i < MFR; ++i)
      ra[i] = *reinterpret_cast<const f32x4*>(Af + (size_t)(tok0 + m0 + sr + 32 * i) * KDIM + k0 + (sc >> 1));
  };
  auto writeA_reg = [&](int buf) {
    char* ab = smem + buf * A_BYTES;
    #pragma unroll
    for (int i = 0; i < MFR; ++i) {
      u32x2 p;
      p[0] = cvt_pk_bf16(ra[i][0], ra[i][1]);
      p[1] = cvt_pk_bf16(ra[i][2], ra[i][3]);
      *reinterpret_cast<u32x2*>(ab + (sr + 32 * i) * 64 + (sc ^ ((sr & 3) << 4))) = p;
    }
  };

  // compute coords
  const int wm   = (wv >> 1) * (TM / 2);
  const int wn   = (wv & 1) * 64;
  const int lrow = lane & 15;
  const int pa0  = (((lane >> 4) ^ (lane & 3)) << 4);          // A phys block byte off
  const int pb0  = ((((lane >> 4) << 1) ^ (lane & 7)) << 4);   // B phys block (lo half)

  f32x4 acc_[MFR][4];
  #pragma unroll
  for (int i = 0; i < MFR; ++i)
    #pragma unroll
    for (int j = 0; j < 4; ++j)
      acc_[i][j] = (f32x4){0.f, 0.f, 0.f, 0.f};

  auto mfma_step = [&](int cur) {
    const char* ab  = smem + cur * A_BYTES;
    const char* bbp = smem + 2 * A_BYTES + cur * B_BYTES;
    short8 afr[MFR], bfr[4];
    #pragma unroll
    for (int f = 0; f < MFR; ++f)
      afr[f] = *reinterpret_cast<const short8*>(ab + (wm + f * 16 + lrow) * 64 + pa0);
    #pragma unroll
    for (int f = 0; f < 4; ++f) {
      const char* rowp = bbp + (size_t)(wn + f * 16 + lrow) * 128;
      f32x4 lo = *reinterpret_cast<const f32x4*>(rowp + pb0);
      f32x4 hi = *reinterpret_cast<const f32x4*>(rowp + (pb0 ^ 16));
      u32x4 pk;
      pk[0] = cvt_pk_bf16(lo[0], lo[1]);
      pk[1] = cvt_pk_bf16(lo[2], lo[3]);
      pk[2] = cvt_pk_bf16(hi[0], hi[1]);
      pk[3] = cvt_pk_bf16(hi[2], hi[3]);
      bfr[f] = __builtin_bit_cast(short8, pk);
    }
    #pragma unroll
    for (int i = 0; i < MFR; ++i)
      #pragma unroll
      for (int j = 0; j < 4; ++j)
        acc_[i][j] = __builtin_amdgcn_mfma_f32_16x16x32_bf16(afr[i], bfr[j], acc_[i][j], 0, 0, 0);
  };

  // ---- prologue ----
  if constexpr (A_GLDS) stageA(0, 0); else { loadA_reg(0); writeA_reg(0); }
  stageB(0, 0);
  __syncthreads();

  // ---- main loop: pure gl_lds staging issued a full iteration ahead ----
  for (int kt = 0; kt < NT; ++kt) {
    const int cur = kt & 1;
    if (kt + 1 < NT) {
      stageB(cur ^ 1, kt + 1);
      if constexpr (A_GLDS) stageA(cur ^ 1, kt + 1);
      else                  loadA_reg(kt + 1);
    }
    mfma_step(cur);
    if constexpr (!A_GLDS) { if (kt + 1 < NT) writeA_reg(cur ^ 1); }
    __syncthreads();
  }

  // ---- epilogue ----
  float bv[4];
  #pragma unroll
  for (int f = 0; f < 4; ++f)
    bv[f] = bias[bbase + n0 + wn + f * 16 + lrow];

  if constexpr (GELU_OUT) {
    static_assert(TM == 128, "GELU path assumes 128-row tiles");
    unsigned short* hout = (unsigned short*)smem;   // [128][128] bf16 = 32 KB
    #pragma unroll
    for (int i = 0; i < MFR; ++i) {
      const int rbase = wm + i * 16 + (lane >> 4) * 4;
      #pragma unroll
      for (int j = 0; j < 4; ++j) {
        #pragma unroll
        for (int jj = 0; jj < 4; ++jj) {
          float xv = acc_[i][j][jj] + bv[j];
          // tanh-GELU: g = x * sigmoid(2*0.79788456*(x + 0.044715 x^3))
          float y2 = xv * (1.5957691216057308f + 0.07135481627f * xv * xv);
          float g  = xv * __builtin_amdgcn_rcpf(1.0f + __expf(-y2));
          hout[(rbase + jj) * 128 + wn + j * 16 + lrow] = (unsigned short)(cvt_pk_bf16(g, g) & 0xFFFFu);
        }
      }
    }
    __syncthreads();
    unsigned short* Oh = (unsigned short*)Outv;
    #pragma unroll
    for (int it = 0; it < 8; ++it) {
      int row  = it * 16 + (tid >> 4);
      int c    = (tid & 15) * 8;
      int grow = m0 + row;
      if (grow < Me) {
        *reinterpret_cast<short8*>(Oh + (size_t)(tok0 + grow) * NDIM + n0 + c)
          = *reinterpret_cast<const short8*>(hout + row * 128 + c);
      }
    }
  } else {
    float* Of = (float*)Outv;
    constexpr float BS = 1.0f / (float)KS;
    #pragma unroll
    for (int i = 0; i < MFR; ++i) {
      const int rbase = wm + i * 16 + (lane >> 4) * 4;
      #pragma unroll
      for (int jj = 0; jj < 4; ++jj) {
        int grow = m0 + rbase + jj;
        if (grow < Me) {
          #pragma unroll
          for (int j = 0; j < 4; ++j) {
            float v = acc_[i][j][jj] + bv[j] * BS;
            float* p = Of + (size_t)(tok0 + grow) * NDIM + n0 + wn + j * 16 + lrow;
            if constexpr (KS > 1) unsafeAtomicAdd(p, v);
            else                  *p = v;
          }
        }
      }
    }
  }
}

extern "C" void kernel_launch(void* const* d_in, const int* in_sizes, int n_in,
                              void* d_out, int out_size, void* d_ws, size_t ws_size,
                              hipStream_t stream)
{
  const float* x  = (const float*)d_in[0];
  const float* W1 = (const float*)d_in[1];
  const float* b1 = (const float*)d_in[2];
  const float* W2 = (const float*)d_in[3];
  const float* b2 = (const float*)d_in[4];
  float* out = (float*)d_out;

  constexpr size_t H_BYTES  = (size_t)9536 * 4096 * 2;   // h bf16
  constexpr size_t XB_BYTES = (size_t)9536 * 1024 * 2;   // x bf16
  unsigned short* h  = (unsigned short*)d_ws;
  unsigned short* xb = (unsigned short*)((char*)d_ws + H_BYTES);

  const bool use_xb = ws_size >= H_BYTES + XB_BYTES;

  // zero d_out for split-K atomic accumulation
  hipMemsetAsync(d_out, 0, (size_t)out_size * sizeof(float), stream);

  if (use_xb) {
    cvt_bf16_kernel<<<2048, 256, 0, stream>>>(x, xb, 9536 * 1024 / 8);
    // GEMM1: h = gelu(x @ W1^T + b1), 128x128 tiles, GN=4
    expert_gemm<true, true, 128, 4096, 1024, 2, 75 * 32, 1>
        <<<75 * 32, 256, 0, stream>>>((const void*)xb, W1, b1, (void*)h);
  } else {
    expert_gemm<false, true, 128, 4096, 1024, 2, 75 * 32, 1>
        <<<75 * 32, 256, 0, stream>>>((const void*)x, W1, b1, (void*)h);
  }

  // GEMM2: out = h @ W2^T + b2, 128x128 tiles, split-K KS=2 (K-chunk 2048, NT=64),
  // atomic fp32 accumulate, bias/2 folded per chunk. 75 m x 8 n x 2 chunks = 1200 blocks.
  expert_gemm<true, false, 128, 1024, 4096, 0, 2 * 75 * 8, 2>
      <<<2 * 75 * 8, 256, 0, stream>>>((const void*)h, W2, b2, (void*)out);
}